// Round 3
// baseline (282.699 us; speedup 1.0000x reference)
//
#include <hip/hip_runtime.h>
#include <math.h>

#define N_NODES 50000
#define F 64
#define OUTF 32
#define NX2 (N_NODES * 32)          // packed bf16-pair count of x
#define NPREP (16384 + 2048 + 128 + 32)

typedef __bf16 v8bf __attribute__((ext_vector_type(8)));
typedef float v4f __attribute__((ext_vector_type(4)));

static __device__ __forceinline__ unsigned short f2bf(float f) {
    union { float f; unsigned u; } v; v.f = f;
    unsigned r = v.u + 0x7FFFu + ((v.u >> 16) & 1u);   // round-to-nearest-even
    return (unsigned short)(r >> 16);
}
static __device__ __forceinline__ float bf2f(unsigned short h) {
    union { unsigned u; float f; } v; v.u = ((unsigned)h) << 16;
    return v.f;
}

// ---------------- fused pre-pass: cast x->bf16 | degree/count histograms | weight prep ----------------
__global__ void pre_kernel(const float2* __restrict__ x2, unsigned int* __restrict__ xb2,
                           const int* __restrict__ src, const int* __restrict__ dst,
                           const float* __restrict__ ew,
                           float* __restrict__ degW, unsigned int* __restrict__ cnt,
                           const float* __restrict__ Wxz0, const float* __restrict__ Wxz1,
                           const float* __restrict__ Wxh0, const float* __restrict__ Wxh1,
                           const float* __restrict__ Wlin,
                           const float* __restrict__ bxz, const float* __restrict__ bhz,
                           const float* __restrict__ bxh, const float* __restrict__ bhh,
                           const float* __restrict__ blin,
                           unsigned short* __restrict__ Bt, unsigned short* __restrict__ Wlt,
                           float* __restrict__ bzc, float* __restrict__ blc, int E) {
    int i = blockIdx.x * 256 + threadIdx.x;
    if (i < NX2) {
        float2 v = x2[i];
        xb2[i] = (unsigned)f2bf(v.x) | ((unsigned)f2bf(v.y) << 16);
    } else if (i < NX2 + E) {
        int e = i - NX2;
        int s = src[e], d = dst[e];
        if ((unsigned)s < N_NODES) unsafeAtomicAdd(&degW[s], ew[e]);
        if ((unsigned)d < N_NODES) atomicAdd(&cnt[d], 1u);
    } else {
        int idx = i - NX2 - E;
        if (idx < 16384) {
            int k = idx & 127, n = idx >> 7;
            float v;
            if (k < 64) v = (n < 64) ? Wxz0[k * 64 + n] : Wxh0[k * 64 + (n - 64)];
            else        v = (n < 64) ? Wxz1[(k - 64) * 64 + n] : Wxh1[(k - 64) * 64 + (n - 64)];
            Bt[n * 128 + k] = f2bf(v);
        } else if (idx < 16384 + 2048) {
            int j = idx - 16384; int k = j & 63, n = j >> 6;
            Wlt[n * 64 + k] = f2bf(Wlin[k * 32 + n]);
        } else if (idx < 16384 + 2048 + 128) {
            int j = idx - 16384 - 2048;
            bzc[j] = (j < 64) ? (bxz[j] + bhz[j]) : (bxh[j - 64] + bhh[j - 64]);
        } else if (idx < NPREP) {
            int j = idx - 16384 - 2048 - 128;
            blc[j] = blin[j];
        }
    }
}

// ---------------- scan step A: per-256-block exclusive scan of cnt ----------------
__global__ void scanA_kernel(const unsigned int* __restrict__ cnt, unsigned int* __restrict__ off,
                             unsigned int* __restrict__ blockSum) {
    __shared__ unsigned int s[256];
    int t = threadIdx.x;
    int i = blockIdx.x * 256 + t;
    unsigned v = (i < N_NODES) ? cnt[i] : 0u;
    s[t] = v;
    __syncthreads();
    #pragma unroll
    for (int d = 1; d < 256; d <<= 1) {
        unsigned a = (t >= d) ? s[t - d] : 0u;
        __syncthreads();
        s[t] += a;
        __syncthreads();
    }
    if (i < N_NODES) off[i] = s[t] - v;
    if (t == 255) blockSum[blockIdx.x] = s[255];
}

// ---------------- scan step B: scan the 196 block sums ----------------
__global__ void scanB_kernel(const unsigned int* __restrict__ blockSum, unsigned int* __restrict__ blockOff,
                             int nb) {
    __shared__ unsigned int s[256];
    int t = threadIdx.x;
    unsigned v = (t < nb) ? blockSum[t] : 0u;
    s[t] = v;
    __syncthreads();
    #pragma unroll
    for (int d = 1; d < 256; d <<= 1) {
        unsigned a = (t >= d) ? s[t - d] : 0u;
        __syncthreads();
        s[t] += a;
        __syncthreads();
    }
    if (t < nb) blockOff[t] = s[t] - v;
}

// ---------------- scan step C: finalize offsets, init cursor, compute dinv ----------------
__global__ void scanC_kernel(unsigned int* __restrict__ off, const unsigned int* __restrict__ blockOff,
                             unsigned int* __restrict__ cursor,
                             const float* __restrict__ degW, float* __restrict__ dinv) {
    int i = blockIdx.x * 256 + threadIdx.x;
    if (i < N_NODES) {
        unsigned o = off[i] + blockOff[blockIdx.x];
        off[i] = o;
        cursor[i] = o;
        float d = degW[i];
        dinv[i] = d > 0.f ? rsqrtf(d) : 0.f;
    }
}

// ---------------- CSR fill: bucket edges by dst with precomputed coef ----------------
__global__ void fill_kernel(const int* __restrict__ src, const int* __restrict__ dst,
                            const float* __restrict__ w, const float* __restrict__ dinv,
                            unsigned int* __restrict__ cursor, uint2* __restrict__ csr, int E) {
    int e = blockIdx.x * 256 + threadIdx.x;
    if (e >= E) return;
    int s = src[e], d = dst[e];
    if ((unsigned)s >= N_NODES || (unsigned)d >= N_NODES) return;
    float c = -dinv[s] * w[e] * dinv[d];
    unsigned pos = atomicAdd(&cursor[d], 1u);
    csr[pos] = make_uint2((unsigned)s, __float_as_uint(c));
}

// ---------------- propagate: P[d,:] = sum coef * x[s,:]  (gather, no atomics) ----------------
// 32 lanes per node (lane = feature pair), 2 nodes per wave, f32 accumulate
__launch_bounds__(256)
__global__ void propagate_kernel(const unsigned int* __restrict__ off, const unsigned int* __restrict__ cnt,
                                 const uint2* __restrict__ csr, const unsigned int* __restrict__ xb2,
                                 unsigned int* __restrict__ Pb2) {
    int t = blockIdx.x * 256 + threadIdx.x;
    int node = t >> 5;
    int lane = t & 31;
    if (node >= N_NODES) return;
    unsigned beg = off[node];
    int k = (int)cnt[node];
    float ax = 0.f, ay = 0.f;
    for (int i0 = 0; i0 < k; i0 += 32) {
        int take = min(32, k - i0);
        uint2 ed = (lane < take) ? csr[beg + i0 + lane] : make_uint2(0u, 0u);
        for (int j = 0; j < take; ++j) {
            int s2 = __shfl((int)ed.x, j, 32);
            float c = __uint_as_float(__shfl((int)ed.y, j, 32));
            unsigned xv = xb2[(size_t)s2 * 32 + lane];
            ax = fmaf(c, bf2f((unsigned short)(xv & 0xFFFFu)), ax);
            ay = fmaf(c, bf2f((unsigned short)(xv >> 16)), ay);
        }
    }
    Pb2[(size_t)node * 32 + lane] = (unsigned)f2bf(ax) | ((unsigned)f2bf(ay) << 16);
}

// ---------------- fused dense (MFMA): gates GEMM + GRU + linear + L2-normalize ----------------
__launch_bounds__(256, 3)
__global__ void dense_kernel(const unsigned short* __restrict__ xb, const unsigned short* __restrict__ Pb,
                             const unsigned short* __restrict__ Bt, const unsigned short* __restrict__ Wlt,
                             const float* __restrict__ bzc, const float* __restrict__ blc,
                             float* __restrict__ out) {
    __shared__ unsigned short Bs[128 * 136];
    __shared__ unsigned short Wls[32 * 80];
    __shared__ unsigned short Hs[4][16 * 80];
    __shared__ float bzs[128], bls[32];

    int tid = threadIdx.x;
    for (int c = tid; c < 4096; c += 256) {
        int n = c >> 5; int k4 = (c & 31) * 4;
        *(uint2*)&Bs[n * 136 + k4] = *(const uint2*)&Bt[n * 128 + k4];
    }
    for (int c = tid; c < 512; c += 256) {
        int n = c >> 4; int k4 = (c & 15) * 4;
        *(uint2*)&Wls[n * 80 + k4] = *(const uint2*)&Wlt[n * 64 + k4];
    }
    if (tid < 128) bzs[tid] = bzc[tid];
    if (tid < 32) bls[tid] = blc[tid];
    __syncthreads();

    int wv = tid >> 6, lane = tid & 63;
    int nl = lane & 15, q = lane >> 4;
    int rowbase = blockIdx.x * 64 + wv * 16;

    int arow = rowbase + nl; if (arow >= N_NODES) arow = N_NODES - 1;
    v4f acc[8];
    #pragma unroll
    for (int i = 0; i < 8; ++i) acc[i] = (v4f)(0.f);

    #pragma unroll
    for (int kk = 0; kk < 4; ++kk) {
        int k0 = kk * 32 + q * 8;
        const unsigned short* ap = (kk < 2) ? (xb + (size_t)arow * 64 + k0)
                                            : (Pb + (size_t)arow * 64 + (k0 - 64));
        v8bf a = *(const v8bf*)ap;
        #pragma unroll
        for (int tn = 0; tn < 8; ++tn) {
            v8bf b = *(const v8bf*)&Bs[(tn * 16 + nl) * 136 + kk * 32 + q * 8];
            acc[tn] = __builtin_amdgcn_mfma_f32_16x16x32_bf16(a, b, acc[tn], 0, 0, 0);
        }
    }

    #pragma unroll
    for (int tn = 0; tn < 4; ++tn) {
        int n = tn * 16 + nl;
        float bz = bzs[n], bh = bzs[64 + n];
        #pragma unroll
        for (int r = 0; r < 4; ++r) {
            float z = acc[tn][r] + bz;
            float h = acc[tn + 4][r] + bh;
            float sg = 1.f / (1.f + __expf(-z));
            float th = 1.f - 2.f / (__expf(2.f * h) + 1.f);
            int m = q * 4 + r;
            Hs[wv][m * 80 + n] = f2bf((1.f - sg) * th);
        }
    }

    v4f acc2[2];
    acc2[0] = (v4f)(0.f); acc2[1] = (v4f)(0.f);
    #pragma unroll
    for (int kk = 0; kk < 2; ++kk) {
        v8bf a = *(const v8bf*)&Hs[wv][nl * 80 + kk * 32 + q * 8];
        #pragma unroll
        for (int tn = 0; tn < 2; ++tn) {
            v8bf b = *(const v8bf*)&Wls[(tn * 16 + nl) * 80 + kk * 32 + q * 8];
            acc2[tn] = __builtin_amdgcn_mfma_f32_16x16x32_bf16(a, b, acc2[tn], 0, 0, 0);
        }
    }

    float o0[4], o1[4];
    #pragma unroll
    for (int r = 0; r < 4; ++r) {
        o0[r] = acc2[0][r] + bls[nl];
        o1[r] = acc2[1][r] + bls[16 + nl];
    }
    #pragma unroll
    for (int r = 0; r < 4; ++r) {
        float ss = o0[r] * o0[r] + o1[r] * o1[r];
        ss += __shfl_xor(ss, 1);
        ss += __shfl_xor(ss, 2);
        ss += __shfl_xor(ss, 4);
        ss += __shfl_xor(ss, 8);
        float dn = fmaxf(sqrtf(ss), 1e-12f);
        int node = rowbase + q * 4 + r;
        if (node < N_NODES) {
            out[node * 32 + nl] = o0[r] / dn;
            out[node * 32 + 16 + nl] = o1[r] / dn;
        }
    }
}

extern "C" void kernel_launch(void* const* d_in, const int* in_sizes, int n_in,
                              void* d_out, int out_size, void* d_ws, size_t ws_size,
                              hipStream_t stream) {
    const float* x    = (const float*)d_in[0];
    const int*   ei   = (const int*)d_in[1];
    const float* ew   = (const float*)d_in[2];
    const float* Wxz0 = (const float*)d_in[3];
    const float* Wxz1 = (const float*)d_in[4];
    const float* bxz  = (const float*)d_in[5];
    const float* bhz  = (const float*)d_in[8];
    const float* Wxh0 = (const float*)d_in[15];
    const float* Wxh1 = (const float*)d_in[16];
    const float* bxh  = (const float*)d_in[17];
    const float* bhh  = (const float*)d_in[20];
    const float* Wlin = (const float*)d_in[21];
    const float* blin = (const float*)d_in[22];
    float* out = (float*)d_out;

    int E = in_sizes[2];
    const int* src = ei;
    const int* dst = ei + E;

    // workspace layout (bytes):
    // [0, 200000)              degW    (f32, zeroed)
    // [200000, 400000)         cnt     (u32, zeroed)
    // [400000, 600000)         dinv    (f32)
    // [600000, 800704)         off     (u32, 50176)
    // [800768, 1000768)        cursor  (u32)
    // [1000960, 1001984)       blockSum(u32 256)
    // [1001984, 1003008)       blockOff(u32 256)
    // [1003008, 1003520)       bzc     (f32 128)
    // [1003520, 1003648)       blc     (f32 32)
    // [1003648, 1036416)       Bt      (bf16 128*128)
    // [1036416, 1040512)       Wlt     (bf16 32*64)
    // [1100000, 7500000)       xb      (bf16 N*64)
    // [7500000, 13900000)      Pb      (bf16 N*64)
    // [13900000, 13900000+E*8) csr     (uint2)
    char* base = (char*)d_ws;
    float*          degW   = (float*)(base + 0);
    unsigned int*   cnt    = (unsigned int*)(base + 200000);
    float*          dinv   = (float*)(base + 400000);
    unsigned int*   off    = (unsigned int*)(base + 600000);
    unsigned int*   cursor = (unsigned int*)(base + 800768);
    unsigned int*   bSum   = (unsigned int*)(base + 1000960);
    unsigned int*   bOff   = (unsigned int*)(base + 1001984);
    float*          bzc    = (float*)(base + 1003008);
    float*          blc    = (float*)(base + 1003520);
    unsigned short* Bt     = (unsigned short*)(base + 1003648);
    unsigned short* Wlt    = (unsigned short*)(base + 1036416);
    unsigned short* xb     = (unsigned short*)(base + 1100000);
    unsigned short* Pb     = (unsigned short*)(base + 7500000);
    uint2*          csr    = (uint2*)(base + 13900000);

    hipMemsetAsync(base, 0, 400000, stream);   // degW + cnt

    int preTot = NX2 + E + NPREP;
    pre_kernel<<<(preTot + 255) / 256, 256, 0, stream>>>(
        (const float2*)x, (unsigned int*)xb, src, dst, ew, degW, cnt,
        Wxz0, Wxz1, Wxh0, Wxh1, Wlin, bxz, bhz, bxh, bhh, blin,
        Bt, Wlt, bzc, blc, E);

    int nb = (N_NODES + 255) / 256;   // 196
    scanA_kernel<<<nb, 256, 0, stream>>>(cnt, off, bSum);
    scanB_kernel<<<1, 256, 0, stream>>>(bSum, bOff, nb);
    scanC_kernel<<<nb, 256, 0, stream>>>(off, bOff, cursor, degW, dinv);

    fill_kernel<<<(E + 255) / 256, 256, 0, stream>>>(src, dst, ew, dinv, cursor, csr, E);
    propagate_kernel<<<(N_NODES * 32 + 255) / 256, 256, 0, stream>>>(
        off, cnt, csr, (const unsigned int*)xb, (unsigned int*)Pb);

    dense_kernel<<<(N_NODES + 63) / 64, 256, 0, stream>>>(xb, Pb, Bt, Wlt, bzc, blc, out);
}